// Round 1
// baseline (223.299 us; speedup 1.0000x reference)
//
#include <hip/hip_runtime.h>
#include <stdint.h>

typedef unsigned short u16;
typedef __attribute__((ext_vector_type(4))) float f32x4;
typedef __attribute__((ext_vector_type(8))) short bf16x8;
typedef __attribute__((ext_vector_type(4))) int i32x4;

#define SEQ 4096
#define DIM 256

__device__ __forceinline__ u16 f2bf(float f) {
  union { float f; uint32_t u; } v; v.f = f;
  uint32_t r = (v.u + 0x7FFFu + ((v.u >> 16) & 1u)) >> 16;
  return (u16)r;
}

__device__ __forceinline__ void gload_lds16(const void* g, void* lds) {
  __builtin_amdgcn_global_load_lds(
      (const __attribute__((address_space(1))) uint32_t*)g,
      (__attribute__((address_space(3))) uint32_t*)lds, 16, 0, 0);
}

// ---------------- weight transpose + bf16 cast (scale folded for Wq) --------
__global__ __launch_bounds__(256) void wt_kernel(const float* __restrict__ Wq,
                                                 const float* __restrict__ Wk,
                                                 const float* __restrict__ Wv,
                                                 u16* __restrict__ wt) {
  int b = blockIdx.x;              // 0..767
  int w = b >> 8;                  // which matrix
  int n = b & 255;                 // output column -> wt row
  const float* W = (w == 0) ? Wq : ((w == 1) ? Wk : Wv);
  float scale = (w == 0) ? 0.0625f : 1.0f;
  int k = threadIdx.x;
  wt[(w * 256 + n) * 256 + k] = f2bf(W[k * 256 + n] * scale);
}

// ---------------- QKV projection ---------------------------------------------
// Q (scaled+bias) and K (bias) row-major bf16 [B*S][256].
// V written per-64-row tile TRANSPOSED: vt[tile][d (256)][m (64)] bf16, linear.
__global__ __launch_bounds__(256) void qkv_kernel(
    const float* __restrict__ x, const float* __restrict__ bq,
    const float* __restrict__ bk, const float* __restrict__ bv,
    const u16* __restrict__ wt, u16* __restrict__ qs, u16* __restrict__ kk,
    char* __restrict__ vt) {
  __shared__ __align__(16) u16 lds_b[16384];  // 32KB staged Wt chunk (swizzled)
  __shared__ __align__(16) u16 lds_v[4096];   // 8KB transpose buffer (swizzled)
  int tid = threadIdx.x;
  int w = tid >> 6, l = tid & 63;
  int a = l & 15, g = l >> 4;
  int rowbase = blockIdx.x * 64;

  // A-fragments: x rows -> bf16, kept in registers for all 3 GEMMs
  bf16x8 afr[8];
  {
    int row = rowbase + w * 16 + a;
    const float* xr = x + (size_t)row * 256;
#pragma unroll
    for (int ks = 0; ks < 8; ++ks) {
      int k0 = ks * 32 + g * 8;
      union { bf16x8 s; u16 u[8]; } fr;
#pragma unroll
      for (int i = 0; i < 8; ++i) fr.u[i] = f2bf(xr[k0 + i]);
      afr[ks] = fr.s;
    }
  }

  for (int w3 = 0; w3 < 3; ++w3) {
    const float* bias = (w3 == 0) ? bq : ((w3 == 1) ? bk : bv);
    for (int qn = 0; qn < 4; ++qn) {
      // stage Wt chunk [64 n-rows][256 k] into LDS, source pre-swizzled
      {
        const u16* src = wt + (w3 * 256 + qn * 64) * 256;
        for (int j = 0; j < 8; ++j) {
          uint32_t inst = w * 8 + j;
          uint32_t flat = inst * 1024 + l * 16;
          uint32_t row = flat >> 9;
          uint32_t c5 = (flat >> 4) & 31;
          uint32_t sc = (c5 & ~7u) | ((c5 ^ row) & 7u);
          gload_lds16(src + row * 256 + sc * 8, ((char*)lds_b) + inst * 1024);
        }
      }
      __syncthreads();
      f32x4 acc[4];
#pragma unroll
      for (int n0 = 0; n0 < 4; ++n0) acc[n0] = (f32x4){0.f, 0.f, 0.f, 0.f};
#pragma unroll
      for (int ks = 0; ks < 8; ++ks) {
#pragma unroll
        for (int n0 = 0; n0 < 4; ++n0) {
          uint32_t row = n0 * 16 + a;
          uint32_t c5 = ks * 4 + g;
          uint32_t sc = (c5 & ~7u) | ((c5 ^ row) & 7u);
          bf16x8 bfr = *(const bf16x8*)((const char*)lds_b + row * 512 + sc * 16);
          acc[n0] = __builtin_amdgcn_mfma_f32_16x16x32_bf16(afr[ks], bfr, acc[n0], 0, 0, 0);
        }
      }
      if (w3 < 2) {
        u16* out = (w3 == 0) ? qs : kk;
        float bscale = (w3 == 0) ? 0.0625f : 1.0f;
#pragma unroll
        for (int n0 = 0; n0 < 4; ++n0) {
          int col = qn * 64 + n0 * 16 + a;
          float bb = bias[col] * bscale;
#pragma unroll
          for (int r = 0; r < 4; ++r) {
            int row = rowbase + w * 16 + g * 4 + r;
            out[(size_t)row * 256 + col] = f2bf(acc[n0][r] + bb);
          }
        }
      } else {
        // V: transpose through LDS, then coalesced global write (linear layout)
#pragma unroll
        for (int n0 = 0; n0 < 4; ++n0) {
          int col = qn * 64 + n0 * 16 + a;
          float bb = bias[col];
          int dl = n0 * 16 + a;  // local d within quarter (0..63)
#pragma unroll
          for (int r = 0; r < 4; ++r) {
            int m = w * 16 + g * 4 + r;  // local row (0..63)
            uint32_t byteoff =
                (uint32_t)dl * 128 + ((((uint32_t)m >> 3) ^ ((uint32_t)dl & 7)) << 4) + (m & 7) * 2;
            *(u16*)((char*)lds_v + byteoff) = f2bf(acc[n0][r] + bb);
          }
        }
        __syncthreads();
        {
          int dl = tid >> 2;  // 0..63
          size_t base = (size_t)blockIdx.x * 32768 + (size_t)(qn * 64 + dl) * 128;
#pragma unroll
          for (int cc = 0; cc < 2; ++cc) {
            uint32_t c = (tid & 3) + cc * 4;
            i32x4 vd = *(const i32x4*)((const char*)lds_v + dl * 128 + ((c ^ (dl & 7)) << 4));
            *(i32x4*)(vt + base + c * 16) = vd;
          }
        }
      }
      __syncthreads();
    }
  }
}

// ---------------- flash attention --------------------------------------------
__global__ __launch_bounds__(256) void attn_kernel(const u16* __restrict__ qs,
                                                   const u16* __restrict__ kk,
                                                   const char* __restrict__ vt,
                                                   float* __restrict__ out) {
  __shared__ __align__(16) char k_lds[32768];  // K tile; P aliased in first 8KB after QK
  __shared__ __align__(16) char v_lds[32768];  // V^T tile
  int tid = threadIdx.x;
  int w = tid >> 6, l = tid & 63;
  int a = l & 15, g = l >> 4;
  int batch = blockIdx.x >> 6;
  int qt = blockIdx.x & 63;
  int qrow = qt * 64 + w * 16 + a;  // within batch

  // Q fragments (pre-scaled by 1/16), kept in registers
  bf16x8 qfr[8];
  {
    const u16* qp = qs + ((size_t)batch * SEQ + qrow) * 256;
#pragma unroll
    for (int ks = 0; ks < 8; ++ks) qfr[ks] = *(const bf16x8*)(qp + ks * 32 + g * 8);
  }

  f32x4 o[16];
#pragma unroll
  for (int i = 0; i < 16; ++i) o[i] = (f32x4){0.f, 0.f, 0.f, 0.f};
  float mr[4], lr[4];
#pragma unroll
  for (int r = 0; r < 4; ++r) { mr[r] = -INFINITY; lr[r] = 0.f; }

  const char* kbase = (const char*)kk + (size_t)batch * SEQ * 512;
  const char* vbase = vt + (size_t)batch * 64 * 32768;

  for (int t = 0; t < 64; ++t) {
    // ---- stage K (rows 512B) and V^T (rows 128B), sources pre-swizzled ----
    {
      const char* ksrc = kbase + (size_t)t * 32768;
      for (int j = 0; j < 8; ++j) {
        uint32_t inst = w * 8 + j;
        uint32_t flat = inst * 1024 + l * 16;
        uint32_t row = flat >> 9;
        uint32_t c5 = (flat >> 4) & 31;
        uint32_t sc = (c5 & ~7u) | ((c5 ^ row) & 7u);
        gload_lds16(ksrc + row * 512 + sc * 16, k_lds + inst * 1024);
      }
      const char* vsrc = vbase + (size_t)t * 32768;
      for (int j = 0; j < 8; ++j) {
        uint32_t inst = w * 8 + j;
        uint32_t flat = inst * 1024 + l * 16;
        uint32_t row = flat >> 7;
        uint32_t c3 = (flat >> 4) & 7;
        uint32_t sc = c3 ^ (row & 7);
        gload_lds16(vsrc + row * 128 + sc * 16, v_lds + inst * 1024);
      }
    }
    __syncthreads();

    // ---- QK^T: scores 16x64 per wave --------------------------------------
    f32x4 sc4[4];
#pragma unroll
    for (int n0 = 0; n0 < 4; ++n0) sc4[n0] = (f32x4){0.f, 0.f, 0.f, 0.f};
#pragma unroll
    for (int ks = 0; ks < 8; ++ks) {
#pragma unroll
      for (int n0 = 0; n0 < 4; ++n0) {
        uint32_t row = n0 * 16 + a;
        uint32_t c5 = ks * 4 + g;
        uint32_t sc = (c5 & ~7u) | ((c5 ^ row) & 7u);
        bf16x8 bfr = *(const bf16x8*)(k_lds + row * 512 + sc * 16);
        sc4[n0] = __builtin_amdgcn_mfma_f32_16x16x32_bf16(qfr[ks], bfr, sc4[n0], 0, 0, 0);
      }
    }
    __syncthreads();  // all K reads done -> P region (alias of k_lds) free

    // ---- online softmax (fp32) --------------------------------------------
    float pvv[4][4];
#pragma unroll
    for (int r = 0; r < 4; ++r) {
      float tm = fmaxf(fmaxf(sc4[0][r], sc4[1][r]), fmaxf(sc4[2][r], sc4[3][r]));
      tm = fmaxf(tm, __shfl_xor(tm, 1));
      tm = fmaxf(tm, __shfl_xor(tm, 2));
      tm = fmaxf(tm, __shfl_xor(tm, 4));
      tm = fmaxf(tm, __shfl_xor(tm, 8));
      float mnew = fmaxf(mr[r], tm);
      float corr = __expf(mr[r] - mnew);
      mr[r] = mnew;
      float rs = 0.f;
#pragma unroll
      for (int n0 = 0; n0 < 4; ++n0) {
        float p = __expf(sc4[n0][r] - mnew);
        pvv[n0][r] = p;
        rs += p;
      }
      rs += __shfl_xor(rs, 1);
      rs += __shfl_xor(rs, 2);
      rs += __shfl_xor(rs, 4);
      rs += __shfl_xor(rs, 8);
      lr[r] = lr[r] * corr + rs;
#pragma unroll
      for (int d0 = 0; d0 < 16; ++d0) o[d0][r] *= corr;
    }

    // ---- write P (bf16) into aliased region, swizzled ---------------------
#pragma unroll
    for (int n0 = 0; n0 < 4; ++n0) {
      int kv = n0 * 16 + a;
#pragma unroll
      for (int r = 0; r < 4; ++r) {
        int q = w * 16 + g * 4 + r;
        uint32_t byteoff =
            (uint32_t)q * 128 + ((((uint32_t)kv >> 3) ^ ((uint32_t)q & 7)) << 4) + (kv & 7) * 2;
        *(u16*)(k_lds + byteoff) = f2bf(pvv[n0][r]);
      }
    }
    // own-wave data: within-wave LDS ordering suffices (no barrier needed)

    // ---- PV: O += P @ V ----------------------------------------------------
    bf16x8 pfr[2];
#pragma unroll
    for (int ks2 = 0; ks2 < 2; ++ks2) {
      int q = w * 16 + a;
      uint32_t c3 = ks2 * 4 + g;
      uint32_t sc = c3 ^ ((uint32_t)q & 7);
      pfr[ks2] = *(const bf16x8*)(k_lds + q * 128 + sc * 16);
    }
#pragma unroll
    for (int d0 = 0; d0 < 16; ++d0) {
#pragma unroll
      for (int ks2 = 0; ks2 < 2; ++ks2) {
        uint32_t row = d0 * 16 + a;
        uint32_t c3 = ks2 * 4 + g;
        uint32_t sc = c3 ^ (row & 7);
        bf16x8 vfr = *(const bf16x8*)(v_lds + row * 128 + sc * 16);
        o[d0] = __builtin_amdgcn_mfma_f32_16x16x32_bf16(pfr[ks2], vfr, o[d0], 0, 0, 0);
      }
    }
    __syncthreads();  // all P/V^T reads done before next tile's staging
  }

  // ---- epilogue: normalize, write fp32 ------------------------------------
  float* op = out + ((size_t)batch * SEQ + (size_t)qt * 64 + w * 16) * 256;
#pragma unroll
  for (int r = 0; r < 4; ++r) {
    float inv = 1.0f / lr[r];
#pragma unroll
    for (int d0 = 0; d0 < 16; ++d0) {
      op[(g * 4 + r) * 256 + d0 * 16 + a] = o[d0][r] * inv;
    }
  }
}

extern "C" void kernel_launch(void* const* d_in, const int* in_sizes, int n_in,
                              void* d_out, int out_size, void* d_ws, size_t ws_size,
                              hipStream_t stream) {
  const float* x = (const float*)d_in[0];
  const float* Wq = (const float*)d_in[1];
  const float* bq = (const float*)d_in[2];
  const float* Wk = (const float*)d_in[3];
  const float* bk = (const float*)d_in[4];
  const float* Wv = (const float*)d_in[5];
  const float* bv = (const float*)d_in[6];
  char* ws = (char*)d_ws;
  u16* wt = (u16*)ws;                              // 3*256*256*2   = 0x60000
  u16* qs = (u16*)(ws + 0x60000);                  // 8MB
  u16* kk = (u16*)(ws + 0x60000 + 0x800000);       // 8MB
  char* vt = ws + 0x60000 + 0x1000000;             // 8MB
  wt_kernel<<<dim3(768), dim3(256), 0, stream>>>(Wq, Wk, Wv, wt);
  qkv_kernel<<<dim3(256), dim3(256), 0, stream>>>(x, bq, bk, bv, wt, qs, kk, vt);
  attn_kernel<<<dim3(256), dim3(256), 0, stream>>>(qs, kk, vt, (float*)d_out);
}